// Round 6
// baseline (716.848 us; speedup 1.0000x reference)
//
#include <hip/hip_runtime.h>
#include <hip/hip_bf16.h>
#include <math.h>

// ---------------------------------------------------------------------------
// RGAT (2 relations) x2 + BatchNorm + head.
//   CSR -> split(x) -> GEMM0 (bf16x3 MFMA) -> logits0 -> agg0 (writes bf16
//   hi/lo directly = GEMM1 A-input) -> BN0 stats (from hi/lo) -> fold BN0
//   into W1 (scl·W1, bias=shf·W1) -> GEMM1 (+cbias) -> logits1 -> agg1 ->
//   BN1 stats -> head (BN1 apply fused).
//   k_agg: EPW edges processed concurrently per wave (2 for C=256, 4 for 128).
// ---------------------------------------------------------------------------

#define WAVE 64

typedef short     s16x8 __attribute__((ext_vector_type(8)));
typedef ushort    u16x8 __attribute__((ext_vector_type(8)));
typedef float     f32x4 __attribute__((ext_vector_type(4)));
typedef _Float16  f16x8 __attribute__((ext_vector_type(8)));

// round-to-nearest-even fp32 -> bf16 bits
__device__ inline ushort bf_rne(float x) {
  uint u = __float_as_uint(x);
  return (ushort)((u + 0x7FFFu + ((u >> 16) & 1u)) >> 16);
}
__device__ inline ushort bf_hi_resid(float x, float& resid) {
  uint u = __float_as_uint(x);
  uint r = (u + 0x7FFFu + ((u >> 16) & 1u)) & 0xFFFF0000u;
  resid = x - __uint_as_float(r);
  return (ushort)(r >> 16);
}
__device__ inline float bf2f(ushort h) {
  return __uint_as_float(((uint)h) << 16);
}

// ---------------- CSR build ----------------
__global__ __launch_bounds__(256) void k_hist(const int* __restrict__ dst,
                                              int* __restrict__ deg, int E) {
  int e = blockIdx.x * blockDim.x + threadIdx.x;
  if (e < E) atomicAdd(&deg[dst[e]], 1);
}

__global__ __launch_bounds__(256) void k_scan_blk(const int* __restrict__ deg,
                                                  int* __restrict__ bsum, int n) {
  int i = blockIdx.x * 256 + threadIdx.x;
  int v = (i < n) ? deg[i] : 0;
#pragma unroll
  for (int o = 32; o; o >>= 1) v += __shfl_xor(v, o);
  __shared__ int ws[4];
  if ((threadIdx.x & 63) == 0) ws[threadIdx.x >> 6] = v;
  __syncthreads();
  if (threadIdx.x == 0) bsum[blockIdx.x] = ws[0] + ws[1] + ws[2] + ws[3];
}

__global__ __launch_bounds__(256) void k_scan_top(int* __restrict__ bsum, int nb,
                                                  int* __restrict__ rowptr_n,
                                                  int E) {
  __shared__ int sh[256];
  int t = threadIdx.x;
  int carry = 0;
  for (int base = 0; base < nb; base += 256) {
    int i = base + t;
    int v = (i < nb) ? bsum[i] : 0;
    sh[t] = v;
    __syncthreads();
    for (int o = 1; o < 256; o <<= 1) {
      int u = (t >= o) ? sh[t - o] : 0;
      __syncthreads();
      sh[t] += u;
      __syncthreads();
    }
    if (i < nb) bsum[i] = carry + sh[t] - v;
    int blockTotal = sh[255];
    __syncthreads();
    carry += blockTotal;
  }
  if (t == 0) *rowptr_n = E;
}

__global__ __launch_bounds__(256) void k_scan_fin(const int* __restrict__ deg,
                                                  const int* __restrict__ bsum,
                                                  int* __restrict__ rowptr,
                                                  int* __restrict__ cursor, int n) {
  int t = threadIdx.x;
  int i = blockIdx.x * 256 + t;
  int v = (i < n) ? deg[i] : 0;
  __shared__ int sh[256];
  sh[t] = v;
  __syncthreads();
  for (int o = 1; o < 256; o <<= 1) {
    int u = (t >= o) ? sh[t - o] : 0;
    __syncthreads();
    sh[t] += u;
    __syncthreads();
  }
  if (i < n) {
    int ex = bsum[blockIdx.x] + sh[t] - v;
    rowptr[i] = ex;
    cursor[i] = ex;
  }
}

__global__ __launch_bounds__(256) void k_scatter(const int* __restrict__ dst,
                                                 int* __restrict__ cursor,
                                                 int* __restrict__ csr, int E) {
  int e = blockIdx.x * blockDim.x + threadIdx.x;
  if (e < E) {
    int p = atomicAdd(&cursor[dst[e]], 1);
    csr[p] = e;
  }
}

// ---------------- fp32 -> bf16 hi/lo split ----------------
__global__ __launch_bounds__(256) void k_split(const float* __restrict__ in,
                                               ushort* __restrict__ hi,
                                               ushort* __restrict__ lo, int n4) {
  int i = blockIdx.x * blockDim.x + threadIdx.x;
  if (i >= n4) return;
  float4 v = ((const float4*)in)[i];
  float r0, r1, r2, r3;
  ushort4 hv, lv;
  hv.x = bf_hi_resid(v.x, r0); lv.x = bf_rne(r0);
  hv.y = bf_hi_resid(v.y, r1); lv.y = bf_rne(r1);
  hv.z = bf_hi_resid(v.z, r2); lv.z = bf_rne(r2);
  hv.w = bf_hi_resid(v.w, r3); lv.w = bf_rne(r3);
  ((ushort4*)hi)[i] = hv;
  ((ushort4*)lo)[i] = lv;
}

// ---------------- W: fp32 [R,K,N] -> transposed bf16 hi/lo [R,N,K] ----------
// optional per-k scale fold (BN0 -> W1)
__global__ __launch_bounds__(256) void k_convW(const float* __restrict__ w,
                                               ushort* __restrict__ thi,
                                               ushort* __restrict__ tlo,
                                               const float* __restrict__ scale,
                                               int R, int K, int N) {
  int i = blockIdx.x * blockDim.x + threadIdx.x;
  if (i >= R * K * N) return;
  int n  = i % N;
  int t  = i / N;
  int kk = t % K;
  int r  = t / K;
  float x = w[i];
  if (scale) x *= scale[kk];
  float resid;
  ushort h = bf_hi_resid(x, resid);
  size_t o = ((size_t)r * N + n) * K + kk;
  thi[o] = h;
  tlo[o] = bf_rne(resid);
}

// ---------------- bias' [R,N] = shf . W  (BN0 shift through W1) ------------
__global__ __launch_bounds__(256) void k_biasW(const float* __restrict__ w,
                                               const float* __restrict__ shf,
                                               float* __restrict__ cbias,
                                               int R, int K, int N) {
  int t = blockIdx.x * blockDim.x + threadIdx.x;
  if (t >= R * N) return;
  int n = t % N, r = t / N;
  float s = 0.f;
  for (int k = 0; k < K; ++k)
    s += shf[k] * w[((size_t)r * K + k) * N + n];
  cbias[t] = s;
}

// ---------------- bf16x3 MFMA GEMM: C[r] = A @ B[r] (+cbias), fp16 out ----
__global__ __launch_bounds__(256) void k_gemm_mfma(
    const ushort* __restrict__ Ahi, const ushort* __restrict__ Alo,
    const ushort* __restrict__ Bhi, const ushort* __restrict__ Blo,
    const float* __restrict__ cbias, _Float16* __restrict__ C,
    int M, int K, int N) {
  const int r  = blockIdx.z;
  const int n0 = blockIdx.x * 128;
  const int m0 = blockIdx.y * 128;
  __shared__ __align__(16) ushort Ah[128][40];
  __shared__ __align__(16) ushort Al[128][40];
  __shared__ __align__(16) ushort Bh[128][40];
  __shared__ __align__(16) ushort Bl[128][40];
  const int tid  = threadIdx.x;
  const int lane = tid & 63;
  const int wid  = tid >> 6;
  const int wr = wid >> 1, wc = wid & 1;
  const int lr = lane & 15;
  const int lk = (lane >> 4) * 8;
  const size_t bbase = (size_t)r * N * K;

  f32x4 acc[4][4];
#pragma unroll
  for (int i = 0; i < 4; ++i)
#pragma unroll
    for (int j = 0; j < 4; ++j) acc[i][j] = (f32x4){0.f, 0.f, 0.f, 0.f};

  for (int k0 = 0; k0 < K; k0 += 32) {
#pragma unroll
    for (int rep = 0; rep < 2; ++rep) {
      int idx = tid + rep * 256;
      int row = idx >> 2, piece = idx & 3;
      int gm = m0 + row;
      s16x8 vh = (s16x8)0, vl = (s16x8)0;
      if (gm < M) {
        size_t ga = (size_t)gm * K + k0 + piece * 8;
        vh = *(const s16x8*)(Ahi + ga);
        vl = *(const s16x8*)(Alo + ga);
      }
      *(s16x8*)&Ah[row][piece * 8] = vh;
      *(s16x8*)&Al[row][piece * 8] = vl;
    }
#pragma unroll
    for (int rep = 0; rep < 2; ++rep) {
      int idx = tid + rep * 256;
      int col = idx >> 2, piece = idx & 3;
      size_t ga = bbase + (size_t)(n0 + col) * K + k0 + piece * 8;
      *(s16x8*)&Bh[col][piece * 8] = *(const s16x8*)(Bhi + ga);
      *(s16x8*)&Bl[col][piece * 8] = *(const s16x8*)(Blo + ga);
    }
    __syncthreads();

    s16x8 ah[4], al[4], bh[4], bl[4];
#pragma unroll
    for (int f = 0; f < 4; ++f) {
      ah[f] = *(const s16x8*)&Ah[wr * 64 + f * 16 + lr][lk];
      al[f] = *(const s16x8*)&Al[wr * 64 + f * 16 + lr][lk];
      bh[f] = *(const s16x8*)&Bh[wc * 64 + f * 16 + lr][lk];
      bl[f] = *(const s16x8*)&Bl[wc * 64 + f * 16 + lr][lk];
    }
#pragma unroll
    for (int fi = 0; fi < 4; ++fi)
#pragma unroll
      for (int fj = 0; fj < 4; ++fj) {
        acc[fi][fj] = __builtin_amdgcn_mfma_f32_16x16x32_bf16(
            ah[fi], bh[fj], acc[fi][fj], 0, 0, 0);
        acc[fi][fj] = __builtin_amdgcn_mfma_f32_16x16x32_bf16(
            ah[fi], bl[fj], acc[fi][fj], 0, 0, 0);
        acc[fi][fj] = __builtin_amdgcn_mfma_f32_16x16x32_bf16(
            al[fi], bh[fj], acc[fi][fj], 0, 0, 0);
      }
    __syncthreads();
  }

  float bz[4] = {0.f, 0.f, 0.f, 0.f};
  if (cbias) {
#pragma unroll
    for (int fj = 0; fj < 4; ++fj)
      bz[fj] = cbias[r * N + n0 + wc * 64 + fj * 16 + lr];
  }
  _Float16* Cr = C + (size_t)r * M * N;
#pragma unroll
  for (int fi = 0; fi < 4; ++fi) {
#pragma unroll
    for (int v = 0; v < 4; ++v) {
      int row = m0 + wr * 64 + fi * 16 + (lane >> 4) * 4 + v;
      if (row < M) {
        size_t rb = (size_t)row * N + n0 + wc * 64 + lr;
#pragma unroll
        for (int fj = 0; fj < 4; ++fj)
          Cr[rb + fj * 16] = (_Float16)(acc[fi][fj][v] + bz[fj]);
      }
    }
  }
}

// ---------------- attention logits from fp16 xw: 4 lanes per row ----------
template <int C, int H>
__global__ __launch_bounds__(256) void k_logits(const _Float16* __restrict__ xw,
                                                const float* __restrict__ qm,
                                                const float* __restrict__ km,
                                                float* __restrict__ ai,
                                                float* __restrict__ aj,
                                                int totalRows) {
  int g = blockIdx.x * blockDim.x + threadIdx.x;
  int row = g >> 2, q4 = g & 3;
  if (row >= totalRows) return;
  constexpr int QC = C / 4;
  const _Float16* rp = xw + (size_t)row * C + q4 * QC;
  float pq[H] = {}, pk[H] = {};
  for (int b = 0; b < QC; b += 8) {
    f16x8 v = *(const f16x8*)(rp + b);
#pragma unroll
    for (int e = 0; e < 8; ++e) {
      float f = (float)v[e];
      int c = q4 * QC + b + e;
#pragma unroll
      for (int h = 0; h < H; ++h) {
        pq[h] += f * qm[c * H + h];
        pk[h] += f * km[c * H + h];
      }
    }
  }
#pragma unroll
  for (int h = 0; h < H; ++h) {
    pq[h] += __shfl_xor(pq[h], 1); pq[h] += __shfl_xor(pq[h], 2);
    pk[h] += __shfl_xor(pk[h], 1); pk[h] += __shfl_xor(pk[h], 2);
  }
  if (q4 == 0) {
#pragma unroll
    for (int h = 0; h < H; ++h) {
      ai[(size_t)row * H + h] = pq[h];
      aj[(size_t)row * H + h] = pk[h];
    }
  }
}

// ---------------- per-dst aggregation, EPW edges concurrent per wave -------
// SPLIT: write bf16 hi/lo (layer-0 -> GEMM1 A-input) else fp32.
template <int C, int H, bool SPLIT>
__global__ __launch_bounds__(256) void k_agg(const int* __restrict__ rowptr,
                                             const int* __restrict__ csr,
                                             const int* __restrict__ srcIdx,
                                             const int* __restrict__ etype,
                                             const float* __restrict__ ai,
                                             const float* __restrict__ aj,
                                             const _Float16* __restrict__ xw,
                                             const float* __restrict__ bias,
                                             float* __restrict__ out32,
                                             ushort* __restrict__ ohi,
                                             ushort* __restrict__ olo,
                                             int nNodes) {
  constexpr int LPE = C / 8;       // lanes per edge-row (32 for 256, 16 for 128)
  constexpr int EPW = WAVE / LPE;  // edges processed concurrently (2 or 4)
  constexpr int OC  = C / H;
  int wid  = (blockIdx.x * blockDim.x + threadIdx.x) >> 6;
  int lane = threadIdx.x & 63;
  if (wid >= nNodes) return;
  const int node  = wid;
  const int start = rowptr[node];
  const int end   = rowptr[node + 1];
  const int deg   = end - start;

  float aiv[2][H];
#pragma unroll
  for (int rr = 0; rr < 2; ++rr)
#pragma unroll
    for (int h = 0; h < H; ++h)
      aiv[rr][h] = ai[((size_t)rr * nNodes + node) * H + h];

  if (deg <= WAVE) {
    // ---- metadata, softmax coefs (lane-parallel over edges) ----
    int i = start + lane;
    bool valid = i < end;
    int e = valid ? csr[i] : 0;
    int s = valid ? srcIdx[e] : 0;
    int t = valid ? etype[e] : 0;
    float a[H], eh[H], m[H], ssum[H];
#pragma unroll
    for (int h = 0; h < H; ++h) {
      float v = aiv[t][h] + aj[((size_t)t * nNodes + s) * H + h];
      v = v > 0.f ? v : 0.2f * v;
      a[h] = valid ? v : -1e30f;
      m[h] = a[h];
    }
#pragma unroll
    for (int h = 0; h < H; ++h)
#pragma unroll
      for (int o = 32; o; o >>= 1) m[h] = fmaxf(m[h], __shfl_xor(m[h], o));
#pragma unroll
    for (int h = 0; h < H; ++h) {
      eh[h] = valid ? expf(a[h] - m[h]) : 0.f;
      ssum[h] = eh[h];
#pragma unroll
      for (int o = 32; o; o >>= 1) ssum[h] += __shfl_xor(ssum[h], o);
    }

    const int sub = lane / LPE;       // edge slot within wave
    const int cl  = lane % LPE;       // channel-lane
    const int c0  = cl * 8;
    const int myhead = c0 / OC;

    float acc[8] = {};
#pragma unroll 2
    for (int j = 0; j < deg; j += EPW) {
      int je = j + sub;
      int   sj = __shfl(s, je);
      int   tj = __shfl(t, je);
      float cc0 = __shfl(eh[0], je);
      float coef;
      if (H == 1) coef = cc0;
      else { float cc1 = __shfl(eh[H - 1], je); coef = myhead ? cc1 : cc0; }
      f16x8 rv = *(const f16x8*)(xw + ((size_t)tj * nNodes + sj) * C + c0);
#pragma unroll
      for (int v = 0; v < 8; ++v) acc[v] += coef * (float)rv[v];
    }
    // merge edge-slot partials
#pragma unroll
    for (int v = 0; v < 8; ++v) {
      if (EPW == 4) acc[v] += __shfl_xor(acc[v], 16);
      acc[v] += __shfl_xor(acc[v], 32);
    }
    float inv = 1.f / (ssum[myhead] + 1e-16f);
    if (sub == 0) {
      if constexpr (SPLIT) {
        u16x8 hv, lv;
#pragma unroll
        for (int v = 0; v < 8; ++v) {
          float xo = acc[v] * inv + bias[c0 + v];
          xo = xo > 0.f ? xo : 0.01f * xo;
          float resid;
          hv[v] = bf_hi_resid(xo, resid);
          lv[v] = bf_rne(resid);
        }
        *(u16x8*)&ohi[(size_t)node * C + c0] = hv;
        *(u16x8*)&olo[(size_t)node * C + c0] = lv;
      } else {
        float ov[8];
#pragma unroll
        for (int v = 0; v < 8; ++v) {
          float xo = acc[v] * inv + bias[c0 + v];
          ov[v] = xo > 0.f ? xo : 0.01f * xo;
        }
        *(float4*)&out32[(size_t)node * C + c0]     = *(float4*)&ov[0];
        *(float4*)&out32[(size_t)node * C + c0 + 4] = *(float4*)&ov[4];
      }
    }
  } else {
    // ---- generic path (rare: deg > 64) ----
    constexpr int VEC = C / WAVE;
    const int myhead = (lane * VEC) / OC;
    float acc[VEC] = {};
    float ssum[H] = {};
    float m[H];
#pragma unroll
    for (int h = 0; h < H; ++h) m[h] = -1e30f;
    for (int i = start + lane; i < end; i += WAVE) {
      int e = csr[i];
      int s = srcIdx[e];
      int t = etype[e];
#pragma unroll
      for (int h = 0; h < H; ++h) {
        float v = aiv[t][h] + aj[((size_t)t * nNodes + s) * H + h];
        v = v > 0.f ? v : 0.2f * v;
        m[h] = fmaxf(m[h], v);
      }
    }
#pragma unroll
    for (int h = 0; h < H; ++h)
#pragma unroll
      for (int o = 32; o; o >>= 1) m[h] = fmaxf(m[h], __shfl_xor(m[h], o));
    for (int base = start; base < end; base += WAVE) {
      int i = base + lane;
      bool valid = i < end;
      int e = valid ? csr[i] : 0;
      int s = valid ? srcIdx[e] : 0;
      int t = valid ? etype[e] : 0;
      float eh[H];
#pragma unroll
      for (int h = 0; h < H; ++h) {
        float v = aiv[t][h] + aj[((size_t)t * nNodes + s) * H + h];
        v = v > 0.f ? v : 0.2f * v;
        eh[h] = valid ? expf(v - m[h]) : 0.f;
        ssum[h] += eh[h];
      }
      int cnt = end - base; if (cnt > WAVE) cnt = WAVE;
#pragma unroll 4
      for (int j = 0; j < cnt; ++j) {
        int   sj = __shfl(s, j);
        int   tj = __shfl(t, j);
        float cc0 = __shfl(eh[0], j);
        float coef;
        if (H == 1) coef = cc0;
        else { float cc1 = __shfl(eh[H - 1], j); coef = myhead ? cc1 : cc0; }
        const _Float16* row = xw + ((size_t)tj * nNodes + sj) * C + lane * VEC;
#pragma unroll
        for (int v = 0; v < VEC; ++v) acc[v] += coef * (float)row[v];
      }
    }
#pragma unroll
    for (int h = 0; h < H; ++h)
#pragma unroll
      for (int o = 32; o; o >>= 1) ssum[h] += __shfl_xor(ssum[h], o);
    float inv = 1.f / (ssum[myhead] + 1e-16f);
#pragma unroll
    for (int v = 0; v < VEC; ++v) {
      int c = lane * VEC + v;
      float xo = acc[v] * inv + bias[c];
      xo = xo > 0.f ? xo : 0.01f * xo;
      if constexpr (SPLIT) {
        float resid;
        ohi[(size_t)node * C + c] = bf_hi_resid(xo, resid);
        olo[(size_t)node * C + c] = bf_rne(resid);
      } else {
        out32[(size_t)node * C + c] = xo;
      }
    }
  }
}

// ---------------- BatchNorm stats (fp32 input) ----------------
__global__ void k_bn_stats(const float* __restrict__ h, double* __restrict__ sum,
                           double* __restrict__ sumsq, int nNodes, int C) {
  int col = threadIdx.x;
  int r0 = blockIdx.x * 256;
  int r1 = r0 + 256; if (r1 > nNodes) r1 = nNodes;
  float s = 0.f, s2 = 0.f;
  for (int r = r0; r < r1; ++r) {
    float v = h[(size_t)r * C + col];
    s += v;
    s2 = fmaf(v, v, s2);
  }
  atomicAdd(&sum[col], (double)s);
  atomicAdd(&sumsq[col], (double)s2);
}

// ---------------- BatchNorm stats (bf16 hi/lo input) ----------------
__global__ void k_bn_stats_hl(const ushort* __restrict__ hi,
                              const ushort* __restrict__ lo,
                              double* __restrict__ sum,
                              double* __restrict__ sumsq, int nNodes, int C) {
  int col = threadIdx.x;
  int r0 = blockIdx.x * 256;
  int r1 = r0 + 256; if (r1 > nNodes) r1 = nNodes;
  float s = 0.f, s2 = 0.f;
  for (int r = r0; r < r1; ++r) {
    size_t o = (size_t)r * C + col;
    float v = bf2f(hi[o]) + bf2f(lo[o]);
    s += v;
    s2 = fmaf(v, v, s2);
  }
  atomicAdd(&sum[col], (double)s);
  atomicAdd(&sumsq[col], (double)s2);
}

__global__ void k_bn_finalize(const double* __restrict__ sum,
                              const double* __restrict__ sumsq,
                              const float* __restrict__ g,
                              const float* __restrict__ be,
                              float* __restrict__ scale,
                              float* __restrict__ shift, int nNodes, int C) {
  int c = blockIdx.x * blockDim.x + threadIdx.x;
  if (c >= C) return;
  double mu  = sum[c] / nNodes;
  double var = sumsq[c] / nNodes - mu * mu;
  float rs = (float)(1.0 / sqrt(var + 1e-5));
  float sc = g[c] * rs;
  scale[c] = sc;
  shift[c] = be[c] - (float)mu * sc;
}

// ---------------- head: gather idx rows, fused BN1 apply, sigmoid ---------
__global__ __launch_bounds__(256) void k_head(const float* __restrict__ h,
                                              const int* __restrict__ idx,
                                              const float* __restrict__ scl,
                                              const float* __restrict__ shf,
                                              const float* __restrict__ wm,
                                              const float* __restrict__ bm,
                                              float* __restrict__ outH,
                                              float* __restrict__ outP, int kSel) {
  int wid  = (blockIdx.x * blockDim.x + threadIdx.x) >> 6;
  int lane = threadIdx.x & 63;
  if (wid >= kSel) return;
  int node = idx[wid];
  const float* row = h + (size_t)node * 128;
  int c = lane * 2;
  float2 v = *(const float2*)&row[c];
  v.x = v.x * scl[c + 0] + shf[c + 0];
  v.y = v.y * scl[c + 1] + shf[c + 1];
  *(float2*)&outH[(size_t)wid * 128 + c] = v;
  float p0 = v.x * wm[c * 5 + 0] + v.y * wm[(c + 1) * 5 + 0];
  float p1 = v.x * wm[c * 5 + 1] + v.y * wm[(c + 1) * 5 + 1];
  float p2 = v.x * wm[c * 5 + 2] + v.y * wm[(c + 1) * 5 + 2];
  float p3 = v.x * wm[c * 5 + 3] + v.y * wm[(c + 1) * 5 + 3];
  float p4 = v.x * wm[c * 5 + 4] + v.y * wm[(c + 1) * 5 + 4];
#pragma unroll
  for (int o = 32; o; o >>= 1) {
    p0 += __shfl_xor(p0, o); p1 += __shfl_xor(p1, o); p2 += __shfl_xor(p2, o);
    p3 += __shfl_xor(p3, o); p4 += __shfl_xor(p4, o);
  }
  if (lane == 0) {
    float lg[5] = {p0 + bm[0], p1 + bm[1], p2 + bm[2], p3 + bm[3], p4 + bm[4]};
    float* o = &outP[(size_t)wid * 5];
    o[0] = 1.f / (1.f + expf(-lg[0]));
    o[1] = 1.f / (1.f + expf(-lg[1]));
    o[2] = 1.f / (1.f + expf(-lg[2]));
    o[3] = 1.f / (1.f + expf(-lg[3]));
    o[4] = 1.f / (1.f + expf(-lg[4]));
  }
}

// ---------------------------------------------------------------------------
extern "C" void kernel_launch(void* const* d_in, const int* in_sizes, int n_in,
                              void* d_out, int out_size, void* d_ws, size_t ws_size,
                              hipStream_t stream) {
  const float* x    = (const float*)d_in[0];
  const int*   ei   = (const int*)d_in[1];
  const int*   etyp = (const int*)d_in[2];
  const int*   idx  = (const int*)d_in[3];
  const float* w0   = (const float*)d_in[4];
  const float* q0   = (const float*)d_in[5];
  const float* k0   = (const float*)d_in[6];
  const float* b0   = (const float*)d_in[7];
  const float* g0   = (const float*)d_in[8];
  const float* be0  = (const float*)d_in[9];
  const float* w1   = (const float*)d_in[10];
  const float* q1   = (const float*)d_in[11];
  const float* k1   = (const float*)d_in[12];
  const float* b1   = (const float*)d_in[13];
  const float* g1   = (const float*)d_in[14];
  const float* be1  = (const float*)d_in[15];
  const float* wm   = (const float*)d_in[16];
  const float* bm   = (const float*)d_in[17];

  const int N    = in_sizes[0] / 128;   // 50000
  const int E    = in_sizes[1] / 2;     // 800000
  const int kSel = in_sizes[3];         // 4096
  const int* srcIdx = ei;
  const int* dstIdx = ei + E;

  size_t off = 0;
  auto carve = [&](size_t bytes) -> void* {
    off = (off + 255) & ~(size_t)255;
    void* p = (char*)d_ws + off;
    off += bytes;
    return p;
  };
  int*      deg    = (int*)carve((size_t)N * 4);
  int*      rowptr = (int*)carve((size_t)(N + 1) * 4);
  int*      cursor = (int*)carve((size_t)N * 4);
  int*      bsum   = (int*)carve((size_t)((N + 255) / 256) * 4);
  int*      csr    = (int*)carve((size_t)E * 4);
  _Float16* xwh    = (_Float16*)carve((size_t)2 * N * 256 * 2);
  ushort*   Ahi    = (ushort*)carve((size_t)N * 256 * 2);
  ushort*   Alo    = (ushort*)carve((size_t)N * 256 * 2);
  ushort*   W0thi  = (ushort*)carve((size_t)2 * 256 * 128 * 2);
  ushort*   W0tlo  = (ushort*)carve((size_t)2 * 256 * 128 * 2);
  ushort*   W1thi  = (ushort*)carve((size_t)2 * 256 * 128 * 2);
  ushort*   W1tlo  = (ushort*)carve((size_t)2 * 256 * 128 * 2);
  float*    cbias1 = (float*)carve(256 * 4);
  float*    ai     = (float*)carve((size_t)2 * N * 2 * 4);
  float*    aj     = (float*)carve((size_t)2 * N * 2 * 4);
  float*    h1     = (float*)carve((size_t)N * 128 * 4);
  double*   dsum   = (double*)carve(256 * 8);
  double*   dsumsq = (double*)carve(256 * 8);
  float*    scl    = (float*)carve(256 * 4);
  float*    shf    = (float*)carve(256 * 4);

  float* outH = (float*)d_out;
  float* outP = outH + (size_t)kSel * 128;

  const int eb = (E + 255) / 256;
  const int nbBlocks = (N + 255) / 256;

  // ---- CSR build ----
  hipMemsetAsync(deg, 0, (size_t)N * 4, stream);
  k_hist<<<eb, 256, 0, stream>>>(dstIdx, deg, E);
  k_scan_blk<<<nbBlocks, 256, 0, stream>>>(deg, bsum, N);
  k_scan_top<<<1, 256, 0, stream>>>(bsum, nbBlocks, rowptr + N, E);
  k_scan_fin<<<nbBlocks, 256, 0, stream>>>(deg, bsum, rowptr, cursor, N);
  k_scatter<<<eb, 256, 0, stream>>>(dstIdx, cursor, csr, E);

  // ---- W0 prep + x split ----
  k_convW<<<(2 * 128 * 256 + 255) / 256, 256, 0, stream>>>(
      w0, W0thi, W0tlo, nullptr, 2, 128, 256);
  k_split<<<((N * 128 / 4) + 255) / 256, 256, 0, stream>>>(
      x, Ahi, Alo, N * 128 / 4);

  // ---- layer 0 ----
  {
    dim3 grid(256 / 128, (N + 127) / 128, 2);
    k_gemm_mfma<<<grid, 256, 0, stream>>>(Ahi, Alo, W0thi, W0tlo, nullptr,
                                          xwh, N, 128, 256);
  }
  k_logits<256, 2><<<(2 * N * 4 + 255) / 256, 256, 0, stream>>>(
      xwh, q0, k0, ai, aj, 2 * N);
  // agg0 writes bf16 hi/lo straight into GEMM1's A buffers
  k_agg<256, 2, true><<<(N * WAVE + 255) / 256, 256, 0, stream>>>(
      rowptr, csr, srcIdx, etyp, ai, aj, xwh, b0, nullptr, Ahi, Alo, N);
  hipMemsetAsync(dsum, 0, 256 * 8, stream);
  hipMemsetAsync(dsumsq, 0, 256 * 8, stream);
  k_bn_stats_hl<<<nbBlocks, 256, 0, stream>>>(Ahi, Alo, dsum, dsumsq, N, 256);
  k_bn_finalize<<<1, 256, 0, stream>>>(dsum, dsumsq, g0, be0, scl, shf, N, 256);

  // ---- fold BN0 into W1 ----
  k_convW<<<(2 * 256 * 128 + 255) / 256, 256, 0, stream>>>(
      w1, W1thi, W1tlo, scl, 2, 256, 128);
  k_biasW<<<1, 256, 0, stream>>>(w1, shf, cbias1, 2, 256, 128);

  // ---- layer 1 ----
  {
    dim3 grid(128 / 128, (N + 127) / 128, 2);
    k_gemm_mfma<<<grid, 256, 0, stream>>>(Ahi, Alo, W1thi, W1tlo, cbias1,
                                          xwh, N, 256, 128);
  }
  k_logits<128, 1><<<(2 * N * 4 + 255) / 256, 256, 0, stream>>>(
      xwh, q1, k1, ai, aj, 2 * N);
  k_agg<128, 1, false><<<(N * WAVE + 255) / 256, 256, 0, stream>>>(
      rowptr, csr, srcIdx, etyp, ai, aj, xwh, b1, h1, nullptr, nullptr, N);
  hipMemsetAsync(dsum, 0, 128 * 8, stream);
  hipMemsetAsync(dsumsq, 0, 128 * 8, stream);
  k_bn_stats<<<nbBlocks, 128, 0, stream>>>(h1, dsum, dsumsq, N, 128);
  k_bn_finalize<<<1, 128, 0, stream>>>(dsum, dsumsq, g1, be1, scl, shf, N, 128);

  // ---- head (BN1 apply fused) ----
  k_head<<<(kSel * WAVE + 255) / 256, 256, 0, stream>>>(
      h1, idx, scl, shf, wm, bm, outH, outP, kSel);
}

// Round 7
// 651.291 us; speedup vs baseline: 1.1007x; 1.1007x over previous
//
#include <hip/hip_runtime.h>
#include <hip/hip_bf16.h>
#include <math.h>

// ---------------------------------------------------------------------------
// RGAT (2 relations) x2 + BatchNorm + head.
//   CSR -> GEMM0 (bf16x3 MFMA, A split fused from fp32 x) -> logits0 ->
//   agg0 (writes bf16 hi/lo = GEMM1 A-input) -> BN0 stats -> fold BN0 into
//   W1 (scl*W1, cbias=shf.W1) -> GEMM1 (+cbias) -> logits1 -> agg1 ->
//   BN1 stats -> head (BN1 apply fused).
// ---------------------------------------------------------------------------

#define WAVE 64

typedef short     s16x8 __attribute__((ext_vector_type(8)));
typedef ushort    u16x8 __attribute__((ext_vector_type(8)));
typedef float     f32x4 __attribute__((ext_vector_type(4)));
typedef _Float16  f16x8 __attribute__((ext_vector_type(8)));

__device__ inline ushort bf_rne(float x) {
  uint u = __float_as_uint(x);
  return (ushort)((u + 0x7FFFu + ((u >> 16) & 1u)) >> 16);
}
__device__ inline ushort bf_hi_resid(float x, float& resid) {
  uint u = __float_as_uint(x);
  uint r = (u + 0x7FFFu + ((u >> 16) & 1u)) & 0xFFFF0000u;
  resid = x - __uint_as_float(r);
  return (ushort)(r >> 16);
}
__device__ inline float bf2f(ushort h) {
  return __uint_as_float(((uint)h) << 16);
}

// ---------------- CSR build ----------------
__global__ __launch_bounds__(256) void k_hist(const int* __restrict__ dst,
                                              int* __restrict__ deg, int E) {
  int e = blockIdx.x * blockDim.x + threadIdx.x;
  if (e < E) atomicAdd(&deg[dst[e]], 1);
}

__global__ __launch_bounds__(256) void k_scan_blk(const int* __restrict__ deg,
                                                  int* __restrict__ bsum, int n) {
  int i = blockIdx.x * 256 + threadIdx.x;
  int v = (i < n) ? deg[i] : 0;
#pragma unroll
  for (int o = 32; o; o >>= 1) v += __shfl_xor(v, o);
  __shared__ int ws[4];
  if ((threadIdx.x & 63) == 0) ws[threadIdx.x >> 6] = v;
  __syncthreads();
  if (threadIdx.x == 0) bsum[blockIdx.x] = ws[0] + ws[1] + ws[2] + ws[3];
}

__global__ __launch_bounds__(256) void k_scan_top(int* __restrict__ bsum, int nb,
                                                  int* __restrict__ rowptr_n,
                                                  int E) {
  __shared__ int sh[256];
  int t = threadIdx.x;
  int carry = 0;
  for (int base = 0; base < nb; base += 256) {
    int i = base + t;
    int v = (i < nb) ? bsum[i] : 0;
    sh[t] = v;
    __syncthreads();
    for (int o = 1; o < 256; o <<= 1) {
      int u = (t >= o) ? sh[t - o] : 0;
      __syncthreads();
      sh[t] += u;
      __syncthreads();
    }
    if (i < nb) bsum[i] = carry + sh[t] - v;
    int blockTotal = sh[255];
    __syncthreads();
    carry += blockTotal;
  }
  if (t == 0) *rowptr_n = E;
}

__global__ __launch_bounds__(256) void k_scan_fin(const int* __restrict__ deg,
                                                  const int* __restrict__ bsum,
                                                  int* __restrict__ rowptr,
                                                  int* __restrict__ cursor, int n) {
  int t = threadIdx.x;
  int i = blockIdx.x * 256 + t;
  int v = (i < n) ? deg[i] : 0;
  __shared__ int sh[256];
  sh[t] = v;
  __syncthreads();
  for (int o = 1; o < 256; o <<= 1) {
    int u = (t >= o) ? sh[t - o] : 0;
    __syncthreads();
    sh[t] += u;
    __syncthreads();
  }
  if (i < n) {
    int ex = bsum[blockIdx.x] + sh[t] - v;
    rowptr[i] = ex;
    cursor[i] = ex;
  }
}

__global__ __launch_bounds__(256) void k_scatter(const int* __restrict__ dst,
                                                 int* __restrict__ cursor,
                                                 int* __restrict__ csr, int E) {
  int e = blockIdx.x * blockDim.x + threadIdx.x;
  if (e < E) {
    int p = atomicAdd(&cursor[dst[e]], 1);
    csr[p] = e;
  }
}

// ---------------- W: fp32 [R,K,N] -> transposed bf16 hi/lo [R,N,K] ----------
__global__ __launch_bounds__(256) void k_convW(const float* __restrict__ w,
                                               ushort* __restrict__ thi,
                                               ushort* __restrict__ tlo,
                                               const float* __restrict__ scale,
                                               int R, int K, int N) {
  int i = blockIdx.x * blockDim.x + threadIdx.x;
  if (i >= R * K * N) return;
  int n  = i % N;
  int t  = i / N;
  int kk = t % K;
  int r  = t / K;
  float x = w[i];
  if (scale) x *= scale[kk];
  float resid;
  ushort h = bf_hi_resid(x, resid);
  size_t o = ((size_t)r * N + n) * K + kk;
  thi[o] = h;
  tlo[o] = bf_rne(resid);
}

// ---------------- cbias[R,N] = shf . W1  (parallel: one wave per output) ---
__global__ __launch_bounds__(256) void k_biasW(const float* __restrict__ w,
                                               const float* __restrict__ shf,
                                               float* __restrict__ cbias,
                                               int R, int K, int N) {
  int wid  = (blockIdx.x * blockDim.x + threadIdx.x) >> 6;
  int lane = threadIdx.x & 63;
  if (wid >= R * N) return;
  int n = wid % N, r = wid / N;
  float s = 0.f;
  for (int k = lane; k < K; k += WAVE)
    s += shf[k] * w[((size_t)r * K + k) * N + n];
#pragma unroll
  for (int o = 32; o; o >>= 1) s += __shfl_xor(s, o);
  if (lane == 0) cbias[wid] = s;
}

// ---------------- bf16x3 MFMA GEMM: C[r] = A @ B[r] (+cbias), fp16 out ----
// A32: stage A from fp32 (on-the-fly hi/lo split). Else from Ahi/Alo.
// XCD-bijective block swizzle for L2 locality (m204 formula).
template <bool A32>
__global__ __launch_bounds__(256) void k_gemm_mfma(
    const float* __restrict__ A, const ushort* __restrict__ Ahi,
    const ushort* __restrict__ Alo, const ushort* __restrict__ Bhi,
    const ushort* __restrict__ Blo, const float* __restrict__ cbias,
    _Float16* __restrict__ C, int M, int K, int N) {
  // ---- bijective XCD swizzle ----
  const int nwgx = gridDim.x, nwgy = gridDim.y;
  int nwg = nwgx * nwgy * gridDim.z;
  int lin = blockIdx.x + nwgx * (blockIdx.y + nwgy * blockIdx.z);
  int q = nwg >> 3, rmd = nwg & 7, xcd = lin & 7, pos = lin >> 3;
  int swz = (xcd < rmd) ? xcd * (q + 1) + pos
                        : rmd * (q + 1) + (xcd - rmd) * q + pos;
  const int bx = swz % nwgx;
  const int by = (swz / nwgx) % nwgy;
  const int bz = swz / (nwgx * nwgy);

  const int r  = bz;
  const int n0 = bx * 128;
  const int m0 = by * 128;
  __shared__ __align__(16) ushort Ah[128][40];
  __shared__ __align__(16) ushort Al[128][40];
  __shared__ __align__(16) ushort Bh[128][40];
  __shared__ __align__(16) ushort Bl[128][40];
  const int tid  = threadIdx.x;
  const int lane = tid & 63;
  const int wid  = tid >> 6;
  const int wr = wid >> 1, wc = wid & 1;
  const int lr = lane & 15;
  const int lk = (lane >> 4) * 8;
  const size_t bbase = (size_t)r * N * K;

  f32x4 acc[4][4];
#pragma unroll
  for (int i = 0; i < 4; ++i)
#pragma unroll
    for (int j = 0; j < 4; ++j) acc[i][j] = (f32x4){0.f, 0.f, 0.f, 0.f};

  for (int k0 = 0; k0 < K; k0 += 32) {
#pragma unroll
    for (int rep = 0; rep < 2; ++rep) {
      int idx = tid + rep * 256;
      int row = idx >> 2, piece = idx & 3;
      int gm = m0 + row;
      if constexpr (A32) {
        f32x4 v0 = (f32x4){0.f, 0.f, 0.f, 0.f}, v1 = v0;
        if (gm < M) {
          const float* ga = A + (size_t)gm * K + k0 + piece * 8;
          v0 = *(const f32x4*)ga;
          v1 = *(const f32x4*)(ga + 4);
        }
        u16x8 hv, lv;
        float resid;
#pragma unroll
        for (int e = 0; e < 4; ++e) {
          hv[e] = bf_hi_resid(v0[e], resid); lv[e] = bf_rne(resid);
          hv[e + 4] = bf_hi_resid(v1[e], resid); lv[e + 4] = bf_rne(resid);
        }
        *(u16x8*)&Ah[row][piece * 8] = hv;
        *(u16x8*)&Al[row][piece * 8] = lv;
      } else {
        s16x8 vh = (s16x8)0, vl = (s16x8)0;
        if (gm < M) {
          size_t ga = (size_t)gm * K + k0 + piece * 8;
          vh = *(const s16x8*)(Ahi + ga);
          vl = *(const s16x8*)(Alo + ga);
        }
        *(s16x8*)&Ah[row][piece * 8] = vh;
        *(s16x8*)&Al[row][piece * 8] = vl;
      }
    }
#pragma unroll
    for (int rep = 0; rep < 2; ++rep) {
      int idx = tid + rep * 256;
      int col = idx >> 2, piece = idx & 3;
      size_t ga = bbase + (size_t)(n0 + col) * K + k0 + piece * 8;
      *(s16x8*)&Bh[col][piece * 8] = *(const s16x8*)(Bhi + ga);
      *(s16x8*)&Bl[col][piece * 8] = *(const s16x8*)(Blo + ga);
    }
    __syncthreads();

    s16x8 ah[4], al[4], bh[4], bl[4];
#pragma unroll
    for (int f = 0; f < 4; ++f) {
      ah[f] = *(const s16x8*)&Ah[wr * 64 + f * 16 + lr][lk];
      al[f] = *(const s16x8*)&Al[wr * 64 + f * 16 + lr][lk];
      bh[f] = *(const s16x8*)&Bh[wc * 64 + f * 16 + lr][lk];
      bl[f] = *(const s16x8*)&Bl[wc * 64 + f * 16 + lr][lk];
    }
#pragma unroll
    for (int fi = 0; fi < 4; ++fi)
#pragma unroll
      for (int fj = 0; fj < 4; ++fj) {
        acc[fi][fj] = __builtin_amdgcn_mfma_f32_16x16x32_bf16(
            ah[fi], bh[fj], acc[fi][fj], 0, 0, 0);
        acc[fi][fj] = __builtin_amdgcn_mfma_f32_16x16x32_bf16(
            ah[fi], bl[fj], acc[fi][fj], 0, 0, 0);
        acc[fi][fj] = __builtin_amdgcn_mfma_f32_16x16x32_bf16(
            al[fi], bh[fj], acc[fi][fj], 0, 0, 0);
      }
    __syncthreads();
  }

  float bz4[4] = {0.f, 0.f, 0.f, 0.f};
  if (cbias) {
#pragma unroll
    for (int fj = 0; fj < 4; ++fj)
      bz4[fj] = cbias[r * N + n0 + wc * 64 + fj * 16 + lr];
  }
  _Float16* Cr = C + (size_t)r * M * N;
#pragma unroll
  for (int fi = 0; fi < 4; ++fi) {
#pragma unroll
    for (int v = 0; v < 4; ++v) {
      int row = m0 + wr * 64 + fi * 16 + (lane >> 4) * 4 + v;
      if (row < M) {
        size_t rb = (size_t)row * N + n0 + wc * 64 + lr;
#pragma unroll
        for (int fj = 0; fj < 4; ++fj)
          Cr[rb + fj * 16] = (_Float16)(acc[fi][fj][v] + bz4[fj]);
      }
    }
  }
}

// ---------------- attention logits from fp16 xw: 4 lanes per row ----------
template <int C, int H>
__global__ __launch_bounds__(256) void k_logits(const _Float16* __restrict__ xw,
                                                const float* __restrict__ qm,
                                                const float* __restrict__ km,
                                                float* __restrict__ ai,
                                                float* __restrict__ aj,
                                                int totalRows) {
  int g = blockIdx.x * blockDim.x + threadIdx.x;
  int row = g >> 2, q4 = g & 3;
  if (row >= totalRows) return;
  constexpr int QC = C / 4;
  const _Float16* rp = xw + (size_t)row * C + q4 * QC;
  float pq[H] = {}, pk[H] = {};
  for (int b = 0; b < QC; b += 8) {
    f16x8 v = *(const f16x8*)(rp + b);
#pragma unroll
    for (int e = 0; e < 8; ++e) {
      float f = (float)v[e];
      int c = q4 * QC + b + e;
#pragma unroll
      for (int h = 0; h < H; ++h) {
        pq[h] += f * qm[c * H + h];
        pk[h] += f * km[c * H + h];
      }
    }
  }
#pragma unroll
  for (int h = 0; h < H; ++h) {
    pq[h] += __shfl_xor(pq[h], 1); pq[h] += __shfl_xor(pq[h], 2);
    pk[h] += __shfl_xor(pk[h], 1); pk[h] += __shfl_xor(pk[h], 2);
  }
  if (q4 == 0) {
#pragma unroll
    for (int h = 0; h < H; ++h) {
      ai[(size_t)row * H + h] = pq[h];
      aj[(size_t)row * H + h] = pk[h];
    }
  }
}

// ---------------- per-dst aggregation, EPW edges concurrent per wave -------
template <int C, int H, bool SPLIT>
__global__ __launch_bounds__(256) void k_agg(const int* __restrict__ rowptr,
                                             const int* __restrict__ csr,
                                             const int* __restrict__ srcIdx,
                                             const int* __restrict__ etype,
                                             const float* __restrict__ ai,
                                             const float* __restrict__ aj,
                                             const _Float16* __restrict__ xw,
                                             const float* __restrict__ bias,
                                             float* __restrict__ out32,
                                             ushort* __restrict__ ohi,
                                             ushort* __restrict__ olo,
                                             int nNodes) {
  constexpr int LPE = C / 8;
  constexpr int EPW = WAVE / LPE;
  constexpr int OC  = C / H;
  int wid  = (blockIdx.x * blockDim.x + threadIdx.x) >> 6;
  int lane = threadIdx.x & 63;
  if (wid >= nNodes) return;
  const int node  = wid;
  const int start = rowptr[node];
  const int end   = rowptr[node + 1];
  const int deg   = end - start;

  float aiv[2][H];
#pragma unroll
  for (int rr = 0; rr < 2; ++rr)
#pragma unroll
    for (int h = 0; h < H; ++h)
      aiv[rr][h] = ai[((size_t)rr * nNodes + node) * H + h];

  if (deg <= WAVE) {
    int i = start + lane;
    bool valid = i < end;
    int e = valid ? csr[i] : 0;
    int s = valid ? srcIdx[e] : 0;
    int t = valid ? etype[e] : 0;
    float a[H], eh[H], m[H], ssum[H];
#pragma unroll
    for (int h = 0; h < H; ++h) {
      float v = aiv[t][h] + aj[((size_t)t * nNodes + s) * H + h];
      v = v > 0.f ? v : 0.2f * v;
      a[h] = valid ? v : -1e30f;
      m[h] = a[h];
    }
#pragma unroll
    for (int h = 0; h < H; ++h)
#pragma unroll
      for (int o = 32; o; o >>= 1) m[h] = fmaxf(m[h], __shfl_xor(m[h], o));
#pragma unroll
    for (int h = 0; h < H; ++h) {
      eh[h] = valid ? expf(a[h] - m[h]) : 0.f;
      ssum[h] = eh[h];
#pragma unroll
      for (int o = 32; o; o >>= 1) ssum[h] += __shfl_xor(ssum[h], o);
    }

    const int sub = lane / LPE;
    const int cl  = lane % LPE;
    const int c0  = cl * 8;
    const int myhead = c0 / OC;

    float acc[8] = {};
#pragma unroll 4
    for (int j = 0; j < deg; j += EPW) {
      int je = j + sub;
      int   sj = __shfl(s, je);
      int   tj = __shfl(t, je);
      float cc0 = __shfl(eh[0], je);
      float coef;
      if (H == 1) coef = cc0;
      else { float cc1 = __shfl(eh[H - 1], je); coef = myhead ? cc1 : cc0; }
      f16x8 rv = *(const f16x8*)(xw + ((size_t)tj * nNodes + sj) * C + c0);
#pragma unroll
      for (int v = 0; v < 8; ++v) acc[v] += coef * (float)rv[v];
    }
#pragma unroll
    for (int v = 0; v < 8; ++v) {
      if (EPW == 4) acc[v] += __shfl_xor(acc[v], 16);
      acc[v] += __shfl_xor(acc[v], 32);
    }
    float inv = 1.f / (ssum[myhead] + 1e-16f);
    if (sub == 0) {
      if constexpr (SPLIT) {
        u16x8 hv, lv;
#pragma unroll
        for (int v = 0; v < 8; ++v) {
          float xo = acc[v] * inv + bias[c0 + v];
          xo = xo > 0.f ? xo : 0.01f * xo;
          float resid;
          hv[v] = bf_hi_resid(xo, resid);
          lv[v] = bf_rne(resid);
        }
        *(u16x8*)&ohi[(size_t)node * C + c0] = hv;
        *(u16x8*)&olo[(size_t)node * C + c0] = lv;
      } else {
        float ov[8];
#pragma unroll
        for (int v = 0; v < 8; ++v) {
          float xo = acc[v] * inv + bias[c0 + v];
          ov[v] = xo > 0.f ? xo : 0.01f * xo;
        }
        *(float4*)&out32[(size_t)node * C + c0]     = *(float4*)&ov[0];
        *(float4*)&out32[(size_t)node * C + c0 + 4] = *(float4*)&ov[4];
      }
    }
  } else {
    constexpr int VEC = C / WAVE;
    const int myhead = (lane * VEC) / OC;
    float acc[VEC] = {};
    float ssum[H] = {};
    float m[H];
#pragma unroll
    for (int h = 0; h < H; ++h) m[h] = -1e30f;
    for (int i = start + lane; i < end; i += WAVE) {
      int e = csr[i];
      int s = srcIdx[e];
      int t = etype[e];
#pragma unroll
      for (int h = 0; h < H; ++h) {
        float v = aiv[t][h] + aj[((size_t)t * nNodes + s) * H + h];
        v = v > 0.f ? v : 0.2f * v;
        m[h] = fmaxf(m[h], v);
      }
    }
#pragma unroll
    for (int h = 0; h < H; ++h)
#pragma unroll
      for (int o = 32; o; o >>= 1) m[h] = fmaxf(m[h], __shfl_xor(m[h], o));
    for (int base = start; base < end; base += WAVE) {
      int i = base + lane;
      bool valid = i < end;
      int e = valid ? csr[i] : 0;
      int s = valid ? srcIdx[e] : 0;
      int t = valid ? etype[e] : 0;
      float eh[H];
#pragma unroll
      for (int h = 0; h < H; ++h) {
        float v = aiv[t][h] + aj[((size_t)t * nNodes + s) * H + h];
        v = v > 0.f ? v : 0.2f * v;
        eh[h] = valid ? expf(v - m[h]) : 0.f;
        ssum[h] += eh[h];
      }
      int cnt = end - base; if (cnt > WAVE) cnt = WAVE;
#pragma unroll 4
      for (int j = 0; j < cnt; ++j) {
        int   sj = __shfl(s, j);
        int   tj = __shfl(t, j);
        float cc0 = __shfl(eh[0], j);
        float coef;
        if (H == 1) coef = cc0;
        else { float cc1 = __shfl(eh[H - 1], j); coef = myhead ? cc1 : cc0; }
        const _Float16* row = xw + ((size_t)tj * nNodes + sj) * C + lane * VEC;
#pragma unroll
        for (int v = 0; v < VEC; ++v) acc[v] += coef * (float)row[v];
      }
    }
#pragma unroll
    for (int h = 0; h < H; ++h)
#pragma unroll
      for (int o = 32; o; o >>= 1) ssum[h] += __shfl_xor(ssum[h], o);
    float inv = 1.f / (ssum[myhead] + 1e-16f);
#pragma unroll
    for (int v = 0; v < VEC; ++v) {
      int c = lane * VEC + v;
      float xo = acc[v] * inv + bias[c];
      xo = xo > 0.f ? xo : 0.01f * xo;
      if constexpr (SPLIT) {
        float resid;
        ohi[(size_t)node * C + c] = bf_hi_resid(xo, resid);
        olo[(size_t)node * C + c] = bf_rne(resid);
      } else {
        out32[(size_t)node * C + c] = xo;
      }
    }
  }
}

// ---------------- BatchNorm stats ----------------
__global__ void k_bn_stats(const float* __restrict__ h, double* __restrict__ sum,
                           double* __restrict__ sumsq, int nNodes, int C) {
  int col = threadIdx.x;
  int r0 = blockIdx.x * 256;
  int r1 = r0 + 256; if (r1 > nNodes) r1 = nNodes;
  float s = 0.f, s2 = 0.f;
  for (int r = r0; r < r1; ++r) {
    float v = h[(size_t)r * C + col];
    s += v;
    s2 = fmaf(v, v, s2);
  }
  atomicAdd(&sum[col], (double)s);
  atomicAdd(&sumsq[col], (double)s2);
}

__global__ void k_bn_stats_hl(const ushort* __restrict__ hi,
                              const ushort* __restrict__ lo,
                              double* __restrict__ sum,
                              double* __restrict__ sumsq, int nNodes, int C) {
  int col = threadIdx.x;
  int r0 = blockIdx.x * 256;
  int r1 = r0 + 256; if (r1 > nNodes) r1 = nNodes;
  float s = 0.f, s2 = 0.f;
  for (int r = r0; r < r1; ++r) {
    size_t o = (size_t)r * C + col;
    float v = bf2f(hi[o]) + bf2f(lo[o]);
    s += v;
    s2 = fmaf(v, v, s2);
  }
  atomicAdd(&sum[col], (double)s);
  atomicAdd(&sumsq[col], (double)s2);
}

__global__ void k_bn_finalize(const double* __restrict__ sum,
                              const double* __restrict__ sumsq,
                              const float* __restrict__ g,
                              const float* __restrict__ be,
                              float* __restrict__ scale,
                              float* __restrict__ shift, int nNodes, int C) {
  int c = blockIdx.x * blockDim.x + threadIdx.x;
  if (c >= C) return;
  double mu  = sum[c] / nNodes;
  double var = sumsq[c] / nNodes - mu * mu;
  float rs = (float)(1.0 / sqrt(var + 1e-5));
  float sc = g[c] * rs;
  scale[c] = sc;
  shift[c] = be[c] - (float)mu * sc;
}

// ---------------- head: gather idx rows, fused BN1 apply, sigmoid ---------
__global__ __launch_bounds__(256) void k_head(const float* __restrict__ h,
                                              const int* __restrict__ idx,
                                              const float* __restrict__ scl,
                                              const float* __restrict__ shf,
                                              const float* __restrict__ wm,
                                              const float* __restrict__ bm,
                                              float* __restrict__ outH,
                                              float* __restrict__ outP, int kSel) {
  int wid  = (blockIdx.x * blockDim.x + threadIdx.x) >> 6;
  int lane = threadIdx.x & 63;
  if (wid >= kSel) return;
  int node = idx[wid];
  const float* row = h + (size_t)node * 128;
  int c = lane * 2;
  float2 v = *(const float2*)&row[c];
  v.x = v.x * scl[c + 0] + shf[c + 0];
  v.y = v.y * scl[c + 1] + shf[c + 1];
  *(float2*)&outH[(size_t)wid * 128 + c] = v;
  float p0 = v.x * wm[c * 5 + 0] + v.y * wm[(c + 1) * 5 + 0];
  float p1 = v.x * wm[c * 5 + 1] + v.y * wm[(c + 1) * 5 + 1];
  float p2 = v.x * wm[c * 5 + 2] + v.y * wm[(c + 1) * 5 + 2];
  float p3 = v.x * wm[c * 5 + 3] + v.y * wm[(c + 1) * 5 + 3];
  float p4 = v.x * wm[c * 5 + 4] + v.y * wm[(c + 1) * 5 + 4];
#pragma unroll
  for (int o = 32; o; o >>= 1) {
    p0 += __shfl_xor(p0, o); p1 += __shfl_xor(p1, o); p2 += __shfl_xor(p2, o);
    p3 += __shfl_xor(p3, o); p4 += __shfl_xor(p4, o);
  }
  if (lane == 0) {
    float lg[5] = {p0 + bm[0], p1 + bm[1], p2 + bm[2], p3 + bm[3], p4 + bm[4]};
    float* o = &outP[(size_t)wid * 5];
    o[0] = 1.f / (1.f + expf(-lg[0]));
    o[1] = 1.f / (1.f + expf(-lg[1]));
    o[2] = 1.f / (1.f + expf(-lg[2]));
    o[3] = 1.f / (1.f + expf(-lg[3]));
    o[4] = 1.f / (1.f + expf(-lg[4]));
  }
}

// ---------------------------------------------------------------------------
extern "C" void kernel_launch(void* const* d_in, const int* in_sizes, int n_in,
                              void* d_out, int out_size, void* d_ws, size_t ws_size,
                              hipStream_t stream) {
  const float* x    = (const float*)d_in[0];
  const int*   ei   = (const int*)d_in[1];
  const int*   etyp = (const int*)d_in[2];
  const int*   idx  = (const int*)d_in[3];
  const float* w0   = (const float*)d_in[4];
  const float* q0   = (const float*)d_in[5];
  const float* k0   = (const float*)d_in[6];
  const float* b0   = (const float*)d_in[7];
  const float* g0   = (const float*)d_in[8];
  const float* be0  = (const float*)d_in[9];
  const float* w1   = (const float*)d_in[10];
  const float* q1   = (const float*)d_in[11];
  const float* k1   = (const float*)d_in[12];
  const float* b1   = (const float*)d_in[13];
  const float* g1   = (const float*)d_in[14];
  const float* be1  = (const float*)d_in[15];
  const float* wm   = (const float*)d_in[16];
  const float* bm   = (const float*)d_in[17];

  const int N    = in_sizes[0] / 128;   // 50000
  const int E    = in_sizes[1] / 2;     // 800000
  const int kSel = in_sizes[3];         // 4096
  const int* srcIdx = ei;
  const int* dstIdx = ei + E;

  size_t off = 0;
  auto carve = [&](size_t bytes) -> void* {
    off = (off + 255) & ~(size_t)255;
    void* p = (char*)d_ws + off;
    off += bytes;
    return p;
  };
  int*      deg    = (int*)carve((size_t)N * 4);
  int*      rowptr = (int*)carve((size_t)(N + 1) * 4);
  int*      cursor = (int*)carve((size_t)N * 4);
  int*      bsum   = (int*)carve((size_t)((N + 255) / 256) * 4);
  int*      csr    = (int*)carve((size_t)E * 4);
  _Float16* xwh    = (_Float16*)carve((size_t)2 * N * 256 * 2);
  ushort*   Ahi    = (ushort*)carve((size_t)N * 256 * 2);
  ushort*   Alo    = (ushort*)carve((size_t)N * 256 * 2);
  ushort*   W0thi  = (ushort*)carve((size_t)2 * 256 * 128 * 2);
  ushort*   W0tlo  = (ushort*)carve((size_t)2 * 256 * 128 * 2);
  ushort*   W1thi  = (ushort*)carve((size_t)2 * 256 * 128 * 2);
  ushort*   W1tlo  = (ushort*)carve((size_t)2 * 256 * 128 * 2);
  float*    cbias1 = (float*)carve(256 * 4);
  float*    ai     = (float*)carve((size_t)2 * N * 2 * 4);
  float*    aj     = (float*)carve((size_t)2 * N * 2 * 4);
  float*    h1     = (float*)carve((size_t)N * 128 * 4);
  double*   dsum   = (double*)carve(256 * 8);
  double*   dsumsq = (double*)carve(256 * 8);
  float*    scl    = (float*)carve(256 * 4);
  float*    shf    = (float*)carve(256 * 4);

  float* outH = (float*)d_out;
  float* outP = outH + (size_t)kSel * 128;

  const int eb = (E + 255) / 256;
  const int nbBlocks = (N + 255) / 256;

  // ---- CSR build ----
  hipMemsetAsync(deg, 0, (size_t)N * 4, stream);
  k_hist<<<eb, 256, 0, stream>>>(dstIdx, deg, E);
  k_scan_blk<<<nbBlocks, 256, 0, stream>>>(deg, bsum, N);
  k_scan_top<<<1, 256, 0, stream>>>(bsum, nbBlocks, rowptr + N, E);
  k_scan_fin<<<nbBlocks, 256, 0, stream>>>(deg, bsum, rowptr, cursor, N);
  k_scatter<<<eb, 256, 0, stream>>>(dstIdx, cursor, csr, E);

  // ---- W0 prep ----
  k_convW<<<(2 * 128 * 256 + 255) / 256, 256, 0, stream>>>(
      w0, W0thi, W0tlo, nullptr, 2, 128, 256);

  // ---- layer 0 (A split fused into GEMM staging) ----
  {
    dim3 grid(256 / 128, (N + 127) / 128, 2);
    k_gemm_mfma<true><<<grid, 256, 0, stream>>>(
        x, nullptr, nullptr, W0thi, W0tlo, nullptr, xwh, N, 128, 256);
  }
  k_logits<256, 2><<<(2 * N * 4 + 255) / 256, 256, 0, stream>>>(
      xwh, q0, k0, ai, aj, 2 * N);
  k_agg<256, 2, true><<<(N * WAVE + 255) / 256, 256, 0, stream>>>(
      rowptr, csr, srcIdx, etyp, ai, aj, xwh, b0, nullptr, Ahi, Alo, N);
  hipMemsetAsync(dsum, 0, 256 * 8, stream);
  hipMemsetAsync(dsumsq, 0, 256 * 8, stream);
  k_bn_stats_hl<<<nbBlocks, 256, 0, stream>>>(Ahi, Alo, dsum, dsumsq, N, 256);
  k_bn_finalize<<<1, 256, 0, stream>>>(dsum, dsumsq, g0, be0, scl, shf, N, 256);

  // ---- fold BN0 into W1 ----
  k_convW<<<(2 * 256 * 128 + 255) / 256, 256, 0, stream>>>(
      w1, W1thi, W1tlo, scl, 2, 256, 128);
  k_biasW<<<(2 * 128 * WAVE + 255) / 256, 256, 0, stream>>>(
      w1, shf, cbias1, 2, 256, 128);

  // ---- layer 1 ----
  {
    dim3 grid(128 / 128, (N + 127) / 128, 2);
    k_gemm_mfma<false><<<grid, 256, 0, stream>>>(
        nullptr, Ahi, Alo, W1thi, W1tlo, cbias1, xwh, N, 256, 128);
  }
  k_logits<128, 1><<<(2 * N * 4 + 255) / 256, 256, 0, stream>>>(
      xwh, q1, k1, ai, aj, 2 * N);
  k_agg<128, 1, false><<<(N * WAVE + 255) / 256, 256, 0, stream>>>(
      rowptr, csr, srcIdx, etyp, ai, aj, xwh, b1, h1, nullptr, nullptr, N);
  hipMemsetAsync(dsum, 0, 128 * 8, stream);
  hipMemsetAsync(dsumsq, 0, 128 * 8, stream);
  k_bn_stats<<<nbBlocks, 128, 0, stream>>>(h1, dsum, dsumsq, N, 128);
  k_bn_finalize<<<1, 128, 0, stream>>>(dsum, dsumsq, g1, be1, scl, shf, N, 128);

  // ---- head (BN1 apply fused) ----
  k_head<<<(kSel * WAVE + 255) / 256, 256, 0, stream>>>(
      h1, idx, scl, shf, wm, bm, outH, outP, kSel);
}

// Round 10
// 637.443 us; speedup vs baseline: 1.1246x; 1.0217x over previous
//
#include <hip/hip_runtime.h>
#include <hip/hip_bf16.h>
#include <math.h>

// ---------------------------------------------------------------------------
// RGAT (2 relations) x2 + BatchNorm + head.
//   CSR -> GEMM0 (bf16x3 MFMA, A split fused, logits fused in epilogue) ->
//   agg0 (writes bf16 hi/lo = GEMM1 A-input) -> BN0 stats -> fold BN0 into
//   W1 (scl*W1, cbias=shf.W1) -> GEMM1 (+cbias, logits fused) -> agg1 ->
//   BN1 stats -> head (BN1 apply fused).
//   GEMM work order: r fastest -> A-panel shared within an XCD chunk.
//   NOTE (r8 bug): BN stats memset must cover BOTH dsum and dsumsq carves
//   (dsumsq starts 2048 B after dsum) -> always clear 2*256*8 bytes.
// ---------------------------------------------------------------------------

#define WAVE 64

typedef short     s16x8 __attribute__((ext_vector_type(8)));
typedef ushort    u16x8 __attribute__((ext_vector_type(8)));
typedef float     f32x4 __attribute__((ext_vector_type(4)));
typedef _Float16  f16x8 __attribute__((ext_vector_type(8)));

__device__ inline ushort bf_rne(float x) {
  uint u = __float_as_uint(x);
  return (ushort)((u + 0x7FFFu + ((u >> 16) & 1u)) >> 16);
}
__device__ inline ushort bf_hi_resid(float x, float& resid) {
  uint u = __float_as_uint(x);
  uint r = (u + 0x7FFFu + ((u >> 16) & 1u)) & 0xFFFF0000u;
  resid = x - __uint_as_float(r);
  return (ushort)(r >> 16);
}
__device__ inline float bf2f(ushort h) {
  return __uint_as_float(((uint)h) << 16);
}

// ---------------- CSR build ----------------
__global__ __launch_bounds__(256) void k_hist(const int* __restrict__ dst,
                                              int* __restrict__ deg, int E) {
  int e = blockIdx.x * blockDim.x + threadIdx.x;
  if (e < E) atomicAdd(&deg[dst[e]], 1);
}

__global__ __launch_bounds__(256) void k_scan_blk(const int* __restrict__ deg,
                                                  int* __restrict__ bsum, int n) {
  int i = blockIdx.x * 256 + threadIdx.x;
  int v = (i < n) ? deg[i] : 0;
#pragma unroll
  for (int o = 32; o; o >>= 1) v += __shfl_xor(v, o);
  __shared__ int ws[4];
  if ((threadIdx.x & 63) == 0) ws[threadIdx.x >> 6] = v;
  __syncthreads();
  if (threadIdx.x == 0) bsum[blockIdx.x] = ws[0] + ws[1] + ws[2] + ws[3];
}

__global__ __launch_bounds__(256) void k_scan_top(int* __restrict__ bsum, int nb,
                                                  int* __restrict__ rowptr_n,
                                                  int E) {
  __shared__ int sh[256];
  int t = threadIdx.x;
  int carry = 0;
  for (int base = 0; base < nb; base += 256) {
    int i = base + t;
    int v = (i < nb) ? bsum[i] : 0;
    sh[t] = v;
    __syncthreads();
    for (int o = 1; o < 256; o <<= 1) {
      int u = (t >= o) ? sh[t - o] : 0;
      __syncthreads();
      sh[t] += u;
      __syncthreads();
    }
    if (i < nb) bsum[i] = carry + sh[t] - v;
    int blockTotal = sh[255];
    __syncthreads();
    carry += blockTotal;
  }
  if (t == 0) *rowptr_n = E;
}

__global__ __launch_bounds__(256) void k_scan_fin(const int* __restrict__ deg,
                                                  const int* __restrict__ bsum,
                                                  int* __restrict__ rowptr,
                                                  int* __restrict__ cursor, int n) {
  int t = threadIdx.x;
  int i = blockIdx.x * 256 + t;
  int v = (i < n) ? deg[i] : 0;
  __shared__ int sh[256];
  sh[t] = v;
  __syncthreads();
  for (int o = 1; o < 256; o <<= 1) {
    int u = (t >= o) ? sh[t - o] : 0;
    __syncthreads();
    sh[t] += u;
    __syncthreads();
  }
  if (i < n) {
    int ex = bsum[blockIdx.x] + sh[t] - v;
    rowptr[i] = ex;
    cursor[i] = ex;
  }
}

__global__ __launch_bounds__(256) void k_scatter(const int* __restrict__ dst,
                                                 int* __restrict__ cursor,
                                                 int* __restrict__ csr, int E) {
  int e = blockIdx.x * blockDim.x + threadIdx.x;
  if (e < E) {
    int p = atomicAdd(&cursor[dst[e]], 1);
    csr[p] = e;
  }
}

// ---------------- W: fp32 [R,K,N] -> transposed bf16 hi/lo [R,N,K] ----------
__global__ __launch_bounds__(256) void k_convW(const float* __restrict__ w,
                                               ushort* __restrict__ thi,
                                               ushort* __restrict__ tlo,
                                               const float* __restrict__ scale,
                                               int R, int K, int N) {
  int i = blockIdx.x * blockDim.x + threadIdx.x;
  if (i >= R * K * N) return;
  int n  = i % N;
  int t  = i / N;
  int kk = t % K;
  int r  = t / K;
  float x = w[i];
  if (scale) x *= scale[kk];
  float resid;
  ushort h = bf_hi_resid(x, resid);
  size_t o = ((size_t)r * N + n) * K + kk;
  thi[o] = h;
  tlo[o] = bf_rne(resid);
}

// ---------------- cbias[R,N] = shf . W1  (one wave per output) ----
__global__ __launch_bounds__(256) void k_biasW(const float* __restrict__ w,
                                               const float* __restrict__ shf,
                                               float* __restrict__ cbias,
                                               int R, int K, int N) {
  int wid  = (blockIdx.x * blockDim.x + threadIdx.x) >> 6;
  int lane = threadIdx.x & 63;
  if (wid >= R * N) return;
  int n = wid % N, r = wid / N;
  float s = 0.f;
  for (int k = lane; k < K; k += WAVE)
    s += shf[k] * w[((size_t)r * K + k) * N + n];
#pragma unroll
  for (int o = 32; o; o >>= 1) s += __shfl_xor(s, o);
  if (lane == 0) cbias[wid] = s;
}

// ---------------- bf16x3 MFMA GEMM + fused logits epilogue ----------------
// C[r] = A @ B[r] (+cbias), fp16 out; ai/aj += C.q / C.k (atomic partials).
// Work order: r fastest, then nx, then my (A-panel locality per XCD chunk).
template <bool A32, int H>
__global__ __launch_bounds__(256) void k_gemm_mfma(
    const float* __restrict__ A, const ushort* __restrict__ Ahi,
    const ushort* __restrict__ Alo, const ushort* __restrict__ Bhi,
    const ushort* __restrict__ Blo, const float* __restrict__ cbias,
    const float* __restrict__ qm, const float* __restrict__ km,
    float* __restrict__ ai, float* __restrict__ aj,
    _Float16* __restrict__ C, int M, int K, int N) {
  // ---- bijective XCD swizzle ----
  const int NX = gridDim.x, MY = gridDim.y, R = gridDim.z;
  int nwg = NX * MY * R;
  int lin = blockIdx.x + NX * (blockIdx.y + MY * blockIdx.z);
  int q = nwg >> 3, rmd = nwg & 7, xcd = lin & 7, pos = lin >> 3;
  int swz = (xcd < rmd) ? xcd * (q + 1) + pos
                        : rmd * (q + 1) + (xcd - rmd) * q + pos;
  // decode: r fastest, then nx, then my
  const int r  = swz % R;
  const int nx = (swz / R) % NX;
  const int my = swz / (R * NX);
  const int n0 = nx * 128;
  const int m0 = my * 128;

  __shared__ __align__(16) ushort Ah[128][40];
  __shared__ __align__(16) ushort Al[128][40];
  __shared__ __align__(16) ushort Bh[128][40];
  __shared__ __align__(16) ushort Bl[128][40];
  const int tid  = threadIdx.x;
  const int lane = tid & 63;
  const int wid  = tid >> 6;
  const int wr = wid >> 1, wc = wid & 1;
  const int lr = lane & 15;
  const int lk = (lane >> 4) * 8;
  const size_t bbase = (size_t)r * N * K;

  f32x4 acc[4][4];
#pragma unroll
  for (int i = 0; i < 4; ++i)
#pragma unroll
    for (int j = 0; j < 4; ++j) acc[i][j] = (f32x4){0.f, 0.f, 0.f, 0.f};

  for (int k0 = 0; k0 < K; k0 += 32) {
#pragma unroll
    for (int rep = 0; rep < 2; ++rep) {
      int idx = tid + rep * 256;
      int row = idx >> 2, piece = idx & 3;
      int gm = m0 + row;
      if constexpr (A32) {
        f32x4 v0 = (f32x4){0.f, 0.f, 0.f, 0.f}, v1 = v0;
        if (gm < M) {
          const float* ga = A + (size_t)gm * K + k0 + piece * 8;
          v0 = *(const f32x4*)ga;
          v1 = *(const f32x4*)(ga + 4);
        }
        u16x8 hv, lv;
        float resid;
#pragma unroll
        for (int e = 0; e < 4; ++e) {
          hv[e] = bf_hi_resid(v0[e], resid); lv[e] = bf_rne(resid);
          hv[e + 4] = bf_hi_resid(v1[e], resid); lv[e + 4] = bf_rne(resid);
        }
        *(u16x8*)&Ah[row][piece * 8] = hv;
        *(u16x8*)&Al[row][piece * 8] = lv;
      } else {
        s16x8 vh = (s16x8)0, vl = (s16x8)0;
        if (gm < M) {
          size_t ga = (size_t)gm * K + k0 + piece * 8;
          vh = *(const s16x8*)(Ahi + ga);
          vl = *(const s16x8*)(Alo + ga);
        }
        *(s16x8*)&Ah[row][piece * 8] = vh;
        *(s16x8*)&Al[row][piece * 8] = vl;
      }
    }
#pragma unroll
    for (int rep = 0; rep < 2; ++rep) {
      int idx = tid + rep * 256;
      int col = idx >> 2, piece = idx & 3;
      size_t ga = bbase + (size_t)(n0 + col) * K + k0 + piece * 8;
      *(s16x8*)&Bh[col][piece * 8] = *(const s16x8*)(Bhi + ga);
      *(s16x8*)&Bl[col][piece * 8] = *(const s16x8*)(Blo + ga);
    }
    __syncthreads();

    s16x8 ah[4], al[4], bh[4], bl[4];
#pragma unroll
    for (int f = 0; f < 4; ++f) {
      ah[f] = *(const s16x8*)&Ah[wr * 64 + f * 16 + lr][lk];
      al[f] = *(const s16x8*)&Al[wr * 64 + f * 16 + lr][lk];
      bh[f] = *(const s16x8*)&Bh[wc * 64 + f * 16 + lr][lk];
      bl[f] = *(const s16x8*)&Bl[wc * 64 + f * 16 + lr][lk];
    }
#pragma unroll
    for (int fi = 0; fi < 4; ++fi)
#pragma unroll
      for (int fj = 0; fj < 4; ++fj) {
        acc[fi][fj] = __builtin_amdgcn_mfma_f32_16x16x32_bf16(
            ah[fi], bh[fj], acc[fi][fj], 0, 0, 0);
        acc[fi][fj] = __builtin_amdgcn_mfma_f32_16x16x32_bf16(
            ah[fi], bl[fj], acc[fi][fj], 0, 0, 0);
        acc[fi][fj] = __builtin_amdgcn_mfma_f32_16x16x32_bf16(
            al[fi], bh[fj], acc[fi][fj], 0, 0, 0);
      }
    __syncthreads();
  }

  float bz4[4] = {0.f, 0.f, 0.f, 0.f};
  if (cbias) {
#pragma unroll
    for (int fj = 0; fj < 4; ++fj)
      bz4[fj] = cbias[r * N + n0 + wc * 64 + fj * 16 + lr];
  }
  // q/k columns for this lane's cols
  float qv[4][H], kv[4][H];
#pragma unroll
  for (int fj = 0; fj < 4; ++fj) {
    int gn = n0 + wc * 64 + fj * 16 + lr;
#pragma unroll
    for (int h = 0; h < H; ++h) {
      qv[fj][h] = qm[gn * H + h];
      kv[fj][h] = km[gn * H + h];
    }
  }
  _Float16* Cr = C + (size_t)r * M * N;
#pragma unroll
  for (int fi = 0; fi < 4; ++fi) {
#pragma unroll
    for (int v = 0; v < 4; ++v) {
      int row = m0 + wr * 64 + fi * 16 + (lane >> 4) * 4 + v;
      float pq[H], pk[H];
#pragma unroll
      for (int h = 0; h < H; ++h) { pq[h] = 0.f; pk[h] = 0.f; }
      if (row < M) {
        size_t rb = (size_t)row * N + n0 + wc * 64 + lr;
#pragma unroll
        for (int fj = 0; fj < 4; ++fj) {
          float val = acc[fi][fj][v] + bz4[fj];
          Cr[rb + fj * 16] = (_Float16)val;
#pragma unroll
          for (int h = 0; h < H; ++h) {
            pq[h] += val * qv[fj][h];
            pk[h] += val * kv[fj][h];
          }
        }
      }
#pragma unroll
      for (int h = 0; h < H; ++h) {
#pragma unroll
        for (int o = 1; o < 16; o <<= 1) {
          pq[h] += __shfl_xor(pq[h], o);
          pk[h] += __shfl_xor(pk[h], o);
        }
      }
      if (lr == 0 && row < M) {
#pragma unroll
        for (int h = 0; h < H; ++h) {
          atomicAdd(&ai[((size_t)r * M + row) * H + h], pq[h]);
          atomicAdd(&aj[((size_t)r * M + row) * H + h], pk[h]);
        }
      }
    }
  }
}

// ---------------- per-dst aggregation, EPW edges concurrent per wave -------
template <int C, int H, bool SPLIT>
__global__ __launch_bounds__(256) void k_agg(const int* __restrict__ rowptr,
                                             const int* __restrict__ csr,
                                             const int* __restrict__ srcIdx,
                                             const int* __restrict__ etype,
                                             const float* __restrict__ ai,
                                             const float* __restrict__ aj,
                                             const _Float16* __restrict__ xw,
                                             const float* __restrict__ bias,
                                             float* __restrict__ out32,
                                             ushort* __restrict__ ohi,
                                             ushort* __restrict__ olo,
                                             int nNodes) {
  constexpr int LPE = C / 8;
  constexpr int EPW = WAVE / LPE;
  constexpr int OC  = C / H;
  int wid  = (blockIdx.x * blockDim.x + threadIdx.x) >> 6;
  int lane = threadIdx.x & 63;
  if (wid >= nNodes) return;
  const int node  = wid;
  const int start = rowptr[node];
  const int end   = rowptr[node + 1];
  const int deg   = end - start;

  float aiv[2][H];
#pragma unroll
  for (int rr = 0; rr < 2; ++rr)
#pragma unroll
    for (int h = 0; h < H; ++h)
      aiv[rr][h] = ai[((size_t)rr * nNodes + node) * H + h];

  if (deg <= WAVE) {
    int i = start + lane;
    bool valid = i < end;
    int e = valid ? csr[i] : 0;
    int s = valid ? srcIdx[e] : 0;
    int t = valid ? etype[e] : 0;
    float a[H], eh[H], m[H], ssum[H];
#pragma unroll
    for (int h = 0; h < H; ++h) {
      float v = aiv[t][h] + aj[((size_t)t * nNodes + s) * H + h];
      v = v > 0.f ? v : 0.2f * v;
      a[h] = valid ? v : -1e30f;
      m[h] = a[h];
    }
#pragma unroll
    for (int h = 0; h < H; ++h)
#pragma unroll
      for (int o = 32; o; o >>= 1) m[h] = fmaxf(m[h], __shfl_xor(m[h], o));
#pragma unroll
    for (int h = 0; h < H; ++h) {
      eh[h] = valid ? expf(a[h] - m[h]) : 0.f;
      ssum[h] = eh[h];
#pragma unroll
      for (int o = 32; o; o >>= 1) ssum[h] += __shfl_xor(ssum[h], o);
    }

    const int sub = lane / LPE;
    const int cl  = lane % LPE;
    const int c0  = cl * 8;
    const int myhead = c0 / OC;

    float acc[8] = {};
#pragma unroll 4
    for (int j = 0; j < deg; j += EPW) {
      int je = j + sub;
      int   sj = __shfl(s, je);
      int   tj = __shfl(t, je);
      float cc0 = __shfl(eh[0], je);
      float coef;
      if (H == 1) coef = cc0;
      else { float cc1 = __shfl(eh[H - 1], je); coef = myhead ? cc1 : cc0; }
      f16x8 rv = *(const f16x8*)(xw + ((size_t)tj * nNodes + sj) * C + c0);
#pragma unroll
      for (int v = 0; v < 8; ++v) acc[v] += coef * (float)rv[v];
    }
#pragma unroll
    for (int v = 0; v < 8; ++v) {
      if (EPW == 4) acc[v] += __shfl_xor(acc[v], 16);
      acc[v] += __shfl_xor(acc[v], 32);
    }
    float inv = 1.f / (ssum[myhead] + 1e-16f);
    if (sub == 0) {
      if constexpr (SPLIT) {
        u16x8 hv, lv;
#pragma unroll
        for (int v = 0; v < 8; ++v) {
          float xo = acc[v] * inv + bias[c0 + v];
          xo = xo > 0.f ? xo : 0.01f * xo;
          float resid;
          hv[v] = bf_hi_resid(xo, resid);
          lv[v] = bf_rne(resid);
        }
        *(u16x8*)&ohi[(size_t)node * C + c0] = hv;
        *(u16x8*)&olo[(size_t)node * C + c0] = lv;
      } else {
        float ov[8];
#pragma unroll
        for (int v = 0; v < 8; ++v) {
          float xo = acc[v] * inv + bias[c0 + v];
          ov[v] = xo > 0.f ? xo : 0.01f * xo;
        }
        *(float4*)&out32[(size_t)node * C + c0]     = *(float4*)&ov[0];
        *(float4*)&out32[(size_t)node * C + c0 + 4] = *(float4*)&ov[4];
      }
    }
  } else {
    constexpr int VEC = C / WAVE;
    const int myhead = (lane * VEC) / OC;
    float acc[VEC] = {};
    float ssum[H] = {};
    float m[H];
#pragma unroll
    for (int h = 0; h < H; ++h) m[h] = -1e30f;
    for (int i = start + lane; i < end; i += WAVE) {
      int e = csr[i];
      int s = srcIdx[e];
      int t = etype[e];
#pragma unroll
      for (int h = 0; h < H; ++h) {
        float v = aiv[t][h] + aj[((size_t)t * nNodes + s) * H + h];
        v = v > 0.f ? v : 0.2f * v;
        m[h] = fmaxf(m[h], v);
      }
    }
#pragma unroll
    for (int h = 0; h < H; ++h)
#pragma unroll
      for (int o = 32; o; o >>= 1) m[h] = fmaxf(m[h], __shfl_xor(m[h], o));
    for (int base = start; base < end; base += WAVE) {
      int i = base + lane;
      bool valid = i < end;
      int e = valid ? csr[i] : 0;
      int s = valid ? srcIdx[e] : 0;
      int t = valid ? etype[e] : 0;
      float eh[H];
#pragma unroll
      for (int h = 0; h < H; ++h) {
        float v = aiv[t][h] + aj[((size_t)t * nNodes + s) * H + h];
        v = v > 0.f ? v : 0.2f * v;
        eh[h] = valid ? expf(v - m[h]) : 0.f;
        ssum[h] += eh[h];
      }
      int cnt = end - base; if (cnt > WAVE) cnt = WAVE;
#pragma unroll 4
      for (int j = 0; j < cnt; ++j) {
        int   sj = __shfl(s, j);
        int   tj = __shfl(t, j);
        float cc0 = __shfl(eh[0], j);
        float coef;
        if (H == 1) coef = cc0;
        else { float cc1 = __shfl(eh[H - 1], j); coef = myhead ? cc1 : cc0; }
        const _Float16* row = xw + ((size_t)tj * nNodes + sj) * C + lane * VEC;
#pragma unroll
        for (int v = 0; v < VEC; ++v) acc[v] += coef * (float)row[v];
      }
    }
#pragma unroll
    for (int h = 0; h < H; ++h)
#pragma unroll
      for (int o = 32; o; o >>= 1) ssum[h] += __shfl_xor(ssum[h], o);
    float inv = 1.f / (ssum[myhead] + 1e-16f);
#pragma unroll
    for (int v = 0; v < VEC; ++v) {
      int c = lane * VEC + v;
      float xo = acc[v] * inv + bias[c];
      xo = xo > 0.f ? xo : 0.01f * xo;
      if constexpr (SPLIT) {
        float resid;
        ohi[(size_t)node * C + c] = bf_hi_resid(xo, resid);
        olo[(size_t)node * C + c] = bf_rne(resid);
      } else {
        out32[(size_t)node * C + c] = xo;
      }
    }
  }
}

// ---------------- BatchNorm stats ----------------
__global__ void k_bn_stats(const float* __restrict__ h, double* __restrict__ sum,
                           double* __restrict__ sumsq, int nNodes, int C) {
  int col = threadIdx.x;
  int r0 = blockIdx.x * 256;
  int r1 = r0 + 256; if (r1 > nNodes) r1 = nNodes;
  float s = 0.f, s2 = 0.f;
  for (int r = r0; r < r1; ++r) {
    float v = h[(size_t)r * C + col];
    s += v;
    s2 = fmaf(v, v, s2);
  }
  atomicAdd(&sum[col], (double)s);
  atomicAdd(&sumsq[col], (double)s2);
}

__global__ void k_bn_stats_hl(const ushort* __restrict__ hi,
                              const ushort* __restrict__ lo,
                              double* __restrict__ sum,
                              double* __restrict__ sumsq, int nNodes, int C) {
  int col = threadIdx.x;
  int r0 = blockIdx.x * 256;
  int r1 = r0 + 256; if (r1 > nNodes) r1 = nNodes;
  float s = 0.f, s2 = 0.f;
  for (int r = r0; r < r1; ++r) {
    size_t o = (size_t)r * C + col;
    float v = bf2f(hi[o]) + bf2f(lo[o]);
    s += v;
    s2 = fmaf(v, v, s2);
  }
  atomicAdd(&sum[col], (double)s);
  atomicAdd(&sumsq[col], (double)s2);
}

__global__ void k_bn_finalize(const double* __restrict__ sum,
                              const double* __restrict__ sumsq,
                              const float* __restrict__ g,
                              const float* __restrict__ be,
                              float* __restrict__ scale,
                              float* __restrict__ shift, int nNodes, int C) {
  int c = blockIdx.x * blockDim.x + threadIdx.x;
  if (c >= C) return;
  double mu  = sum[c] / nNodes;
  double var = sumsq[c] / nNodes - mu * mu;
  float rs = (float)(1.0 / sqrt(var + 1e-5));
  float sc = g[c] * rs;
  scale[c] = sc;
  shift[c] = be[c] - (float)mu * sc;
}

// ---------------- head: gather idx rows, fused BN1 apply, sigmoid ---------
__global__ __launch_bounds__(256) void k_head(const float* __restrict__ h,
                                              const int* __restrict__ idx,
                                              const float* __restrict__ scl,
                                              const float* __restrict__ shf,
                                              const float* __restrict__ wm,
                                              const float* __restrict__ bm,
                                              float* __restrict__ outH,
                                              float* __restrict__ outP, int kSel) {
  int wid  = (blockIdx.x * blockDim.x + threadIdx.x) >> 6;
  int lane = threadIdx.x & 63;
  if (wid >= kSel) return;
  int node = idx[wid];
  const float* row = h + (size_t)node * 128;
  int c = lane * 2;
  float2 v = *(const float2*)&row[c];
  v.x = v.x * scl[c + 0] + shf[c + 0];
  v.y = v.y * scl[c + 1] + shf[c + 1];
  *(float2*)&outH[(size_t)wid * 128 + c] = v;
  float p0 = v.x * wm[c * 5 + 0] + v.y * wm[(c + 1) * 5 + 0];
  float p1 = v.x * wm[c * 5 + 1] + v.y * wm[(c + 1) * 5 + 1];
  float p2 = v.x * wm[c * 5 + 2] + v.y * wm[(c + 1) * 5 + 2];
  float p3 = v.x * wm[c * 5 + 3] + v.y * wm[(c + 1) * 5 + 3];
  float p4 = v.x * wm[c * 5 + 4] + v.y * wm[(c + 1) * 5 + 4];
#pragma unroll
  for (int o = 32; o; o >>= 1) {
    p0 += __shfl_xor(p0, o); p1 += __shfl_xor(p1, o); p2 += __shfl_xor(p2, o);
    p3 += __shfl_xor(p3, o); p4 += __shfl_xor(p4, o);
  }
  if (lane == 0) {
    float lg[5] = {p0 + bm[0], p1 + bm[1], p2 + bm[2], p3 + bm[3], p4 + bm[4]};
    float* o = &outP[(size_t)wid * 5];
    o[0] = 1.f / (1.f + expf(-lg[0]));
    o[1] = 1.f / (1.f + expf(-lg[1]));
    o[2] = 1.f / (1.f + expf(-lg[2]));
    o[3] = 1.f / (1.f + expf(-lg[3]));
    o[4] = 1.f / (1.f + expf(-lg[4]));
  }
}

// ---------------------------------------------------------------------------
extern "C" void kernel_launch(void* const* d_in, const int* in_sizes, int n_in,
                              void* d_out, int out_size, void* d_ws, size_t ws_size,
                              hipStream_t stream) {
  const float* x    = (const float*)d_in[0];
  const int*   ei   = (const int*)d_in[1];
  const int*   etyp = (const int*)d_in[2];
  const int*   idx  = (const int*)d_in[3];
  const float* w0   = (const float*)d_in[4];
  const float* q0   = (const float*)d_in[5];
  const float* k0   = (const float*)d_in[6];
  const float* b0   = (const float*)d_in[7];
  const float* g0   = (const float*)d_in[8];
  const float* be0  = (const float*)d_in[9];
  const float* w1   = (const float*)d_in[10];
  const float* q1   = (const float*)d_in[11];
  const float* k1   = (const float*)d_in[12];
  const float* b1   = (const float*)d_in[13];
  const float* g1   = (const float*)d_in[14];
  const float* be1  = (const float*)d_in[15];
  const float* wm   = (const float*)d_in[16];
  const float* bm   = (const float*)d_in[17];

  const int N    = in_sizes[0] / 128;   // 50000
  const int E    = in_sizes[1] / 2;     // 800000
  const int kSel = in_sizes[3];         // 4096
  const int* srcIdx = ei;
  const int* dstIdx = ei + E;

  size_t off = 0;
  auto carve = [&](size_t bytes) -> void* {
    off = (off + 255) & ~(size_t)255;
    void* p = (char*)d_ws + off;
    off += bytes;
    return p;
  };
  int*      deg    = (int*)carve((size_t)N * 4);
  int*      rowptr = (int*)carve((size_t)(N + 1) * 4);
  int*      cursor = (int*)carve((size_t)N * 4);
  int*      bsum   = (int*)carve((size_t)((N + 255) / 256) * 4);
  int*      csr    = (int*)carve((size_t)E * 4);
  _Float16* xwh    = (_Float16*)carve((size_t)2 * N * 256 * 2);
  ushort*   Ahi    = (ushort*)carve((size_t)N * 256 * 2);
  ushort*   Alo    = (ushort*)carve((size_t)N * 256 * 2);
  ushort*   W0thi  = (ushort*)carve((size_t)2 * 256 * 128 * 2);
  ushort*   W0tlo  = (ushort*)carve((size_t)2 * 256 * 128 * 2);
  ushort*   W1thi  = (ushort*)carve((size_t)2 * 256 * 128 * 2);
  ushort*   W1tlo  = (ushort*)carve((size_t)2 * 256 * 128 * 2);
  float*    cbias1 = (float*)carve(256 * 4);
  float*    ai     = (float*)carve((size_t)2 * N * 2 * 4);  // 800000 B (256-mult)
  float*    aj     = (float*)carve((size_t)2 * N * 2 * 4);  // contiguous with ai
  float*    h1     = (float*)carve((size_t)N * 128 * 4);
  double*   dsum   = (double*)carve(256 * 8);               // 2048 B (256-mult)
  double*   dsumsq = (double*)carve(256 * 8);               // contiguous
  float*    scl    = (float*)carve(256 * 4);
  float*    shf    = (float*)carve(256 * 4);

  float* outH = (float*)d_out;
  float* outP = outH + (size_t)kSel * 128;

  const int eb = (E + 255) / 256;
  const int nbBlocks = (N + 255) / 256;

  // ---- CSR build ----
  hipMemsetAsync(deg, 0, (size_t)N * 4, stream);
  k_hist<<<eb, 256, 0, stream>>>(dstIdx, deg, E);
  k_scan_blk<<<nbBlocks, 256, 0, stream>>>(deg, bsum, N);
  k_scan_top<<<1, 256, 0, stream>>>(bsum, nbBlocks, rowptr + N, E);
  k_scan_fin<<<nbBlocks, 256, 0, stream>>>(deg, bsum, rowptr, cursor, N);
  k_scatter<<<eb, 256, 0, stream>>>(dstIdx, cursor, csr, E);

  // ---- W0 prep ----
  k_convW<<<(2 * 128 * 256 + 255) / 256, 256, 0, stream>>>(
      w0, W0thi, W0tlo, nullptr, 2, 128, 256);

  // ---- layer 0 (A split + logits fused into GEMM) ----
  hipMemsetAsync(ai, 0, (size_t)2 * 2 * N * 2 * 4, stream);  // ai + aj (full)
  {
    dim3 grid(256 / 128, (N + 127) / 128, 2);
    k_gemm_mfma<true, 2><<<grid, 256, 0, stream>>>(
        x, nullptr, nullptr, W0thi, W0tlo, nullptr, q0, k0, ai, aj,
        xwh, N, 128, 256);
  }
  k_agg<256, 2, true><<<(N * WAVE + 255) / 256, 256, 0, stream>>>(
      rowptr, csr, srcIdx, etyp, ai, aj, xwh, b0, nullptr, Ahi, Alo, N);
  hipMemsetAsync(dsum, 0, 2 * 256 * 8, stream);  // FULL dsum + dsumsq carves
  k_bn_stats_hl<<<nbBlocks, 256, 0, stream>>>(Ahi, Alo, dsum, dsumsq, N, 256);
  k_bn_finalize<<<1, 256, 0, stream>>>(dsum, dsumsq, g0, be0, scl, shf, N, 256);

  // ---- fold BN0 into W1 ----
  k_convW<<<(2 * 256 * 128 + 255) / 256, 256, 0, stream>>>(
      w1, W1thi, W1tlo, scl, 2, 256, 128);
  k_biasW<<<(2 * 128 * WAVE + 255) / 256, 256, 0, stream>>>(
      w1, shf, cbias1, 2, 256, 128);

  // ---- layer 1 (logits fused) ----
  hipMemsetAsync(ai, 0, (size_t)2 * 2 * N * 2 * 4, stream);
  {
    dim3 grid(128 / 128, (N + 127) / 128, 2);
    k_gemm_mfma<false, 1><<<grid, 256, 0, stream>>>(
        nullptr, Ahi, Alo, W1thi, W1tlo, cbias1, q1, k1, ai, aj,
        xwh, N, 256, 128);
  }
  k_agg<128, 1, false><<<(N * WAVE + 255) / 256, 256, 0, stream>>>(
      rowptr, csr, srcIdx, etyp, ai, aj, xwh, b1, h1, nullptr, nullptr, N);
  // FIX (r8 bug): must clear dsumsq too — it starts 2048 B after dsum, so a
  // 2*128*8-byte clear only wiped dsum and left stale layer-0 sumsq.
  hipMemsetAsync(dsum, 0, 2 * 256 * 8, stream);
  k_bn_stats<<<nbBlocks, 128, 0, stream>>>(h1, dsum, dsumsq, N, 128);
  k_bn_finalize<<<1, 128, 0, stream>>>(dsum, dsumsq, g1, be1, scl, shf, N, 128);

  // ---- head (BN1 apply fused) ----
  k_head<<<(kSel * WAVE + 255) / 256, 256, 0, stream>>>(
      h1, idx, scl, shf, wm, bm, outH, outP, kSel);
}